// Round 11
// baseline (539.317 us; speedup 1.0000x reference)
//
#include <hip/hip_runtime.h>
#include <hip/hip_fp16.h>

typedef _Float16 half8 __attribute__((ext_vector_type(8)));
typedef _Float16 half2v __attribute__((ext_vector_type(2)));
typedef float f32x4 __attribute__((ext_vector_type(4)));

#if __has_builtin(__builtin_amdgcn_fdot2)
#define FDOT2(a, b, c) __builtin_amdgcn_fdot2((a), (b), (c), false)
#else
static __device__ __forceinline__ float FDOT2(half2v a, half2v b, float c) {
  return (float)a[0] * (float)b[0] + (float)a[1] * (float)b[1] + c;
}
#endif
#define H2(v8, p) ((half2v){(v8)[2 * (p)], (v8)[2 * (p) + 1]})

// async global->LDS, 16B per lane; dest = lds base (wave-uniform) + lane*16
#define GLOAD_LDS16(gp, lp)                                                        \
  __builtin_amdgcn_global_load_lds(                                                \
      (const __attribute__((address_space(1))) void*)(gp),                         \
      (__attribute__((address_space(3))) void*)(lp), 16, 0, 0)

// 16-lane all-reduce via DPP rotate-accumulate: 4 VALU ops, no LDS pipe.
template <int CTRL>
__device__ __forceinline__ float dpp_add16(float x) {
  int y = __builtin_amdgcn_update_dpp(0, __float_as_int(x), CTRL, 0xf, 0xf, true);
  return x + __int_as_float(y);
}
__device__ __forceinline__ float rowsum16(float x) {
  x = dpp_add16<0x128>(x);  // row_ror:8
  x = dpp_add16<0x124>(x);  // row_ror:4
  x = dpp_add16<0x122>(x);  // row_ror:2
  x = dpp_add16<0x121>(x);  // row_ror:1
  return x;
}

// ---------------- mega prep kernel: x->f16 + weight transposes + f16 casts ----------------
__global__ void prep_kernel(const float* __restrict__ x, _Float16* __restrict__ x16, int nx,
                            const float* __restrict__ Wl1, const float* __restrict__ Wr1,
                            _Float16* __restrict__ WlrT1,
                            const float* __restrict__ Wl2, const float* __restrict__ Wr2,
                            _Float16* __restrict__ WlrT2,
                            const float* __restrict__ Wd1, _Float16* __restrict__ WdT1,
                            const float* __restrict__ Wd2, _Float16* __restrict__ WdT2,
                            const float* __restrict__ We1, _Float16* __restrict__ WeK1,
                            const float* __restrict__ We2, _Float16* __restrict__ WeK2,
                            const float* __restrict__ att1, _Float16* __restrict__ att16_1,
                            const float* __restrict__ att2, _Float16* __restrict__ att16_2) {
  int i = blockIdx.x * 256 + threadIdx.x;
  if (i < nx) { x16[i] = (_Float16)x[i]; return; }
  i -= nx;
  if (i < 1024 * 128) {
    int n = i >> 7, k = i & 127;
    float v = (n < 512) ? Wl1[(size_t)k * 512 + n] : Wr1[(size_t)k * 512 + (n - 512)];
    WlrT1[i] = (_Float16)v; return;
  }
  i -= 1024 * 128;
  if (i < 1024 * 512) {
    int n = i >> 9, k = i & 511;
    float v = (n < 512) ? Wl2[(size_t)k * 512 + n] : Wr2[(size_t)k * 512 + (n - 512)];
    WlrT2[i] = (_Float16)v; return;
  }
  i -= 1024 * 512;
  if (i < 512 * 512) { int n = i >> 9, k = i & 511; WdT1[i] = (_Float16)Wd1[(size_t)k * 512 + n]; return; }
  i -= 512 * 512;
  if (i < 64 * 512)  { int n = i >> 9, k = i & 511; WdT2[i] = (_Float16)Wd2[(size_t)k * 64 + n]; return; }
  i -= 64 * 512;
  if (i < 512 * 16)  { WeK1[i] = (_Float16)We1[i]; return; }   // straight [16][512] cast
  i -= 512 * 16;
  if (i < 512 * 16)  { WeK2[i] = (_Float16)We2[i]; return; }
  i -= 512 * 16;
  if (i < 512)       { att16_1[i] = (_Float16)att1[i]; return; }
  i -= 512;
  if (i < 512)       { att16_2[i] = (_Float16)att2[i]; return; }
}

// ---------------- CSR build ----------------
__global__ void deg_hist_kernel(const int* __restrict__ dst0, int* __restrict__ deg, int E) {
  int i = blockIdx.x * 256 + threadIdx.x;
  if (i < E) atomicAdd(&deg[dst0[i]], 1);
}

__global__ __launch_bounds__(1024) void scan_kernel(const int* __restrict__ deg, int* __restrict__ offs, int N) {
  __shared__ int part[1024];
  int t = threadIdx.x;
  int chunk = (N + 1023) / 1024;
  int b = t * chunk, e = min(b + chunk, N);
  int s = 0;
  for (int i = b; i < e; i++) s += deg[i] + 1;
  part[t] = s;
  __syncthreads();
  for (int off = 1; off < 1024; off <<= 1) {
    int v = (t >= off) ? part[t - off] : 0;
    __syncthreads();
    part[t] += v;
    __syncthreads();
  }
  int run = (t == 0) ? 0 : part[t - 1];
  for (int i = b; i < e; i++) { offs[i] = run; run += deg[i] + 1; }
  if (t == 1023) offs[N] = part[1023];
}

// scatter src + slot-ordered edge attr (f16) in one pass; self-loop slot marked, +12 pad
__global__ void csr_fill_kernel(const int* __restrict__ src0, const int* __restrict__ dst0,
                                const float* __restrict__ ea,
                                const int* __restrict__ offs, const int* __restrict__ deg,
                                int* __restrict__ cnt, int* __restrict__ csr_src,
                                _Float16* __restrict__ eas, int E, int N) {
  int i = blockIdx.x * 256 + threadIdx.x;
  if (i < 12) {
    csr_src[E + N + i] = 0;
#pragma unroll
    for (int k = 0; k < 16; k++) eas[(size_t)(E + N + i) * 16 + k] = (_Float16)0.f;
  }
  if (i < E) {
    int d = dst0[i];
    int p = offs[d] + atomicAdd(&cnt[d], 1);
    csr_src[p] = src0[i];
    const float* s = ea + (size_t)i * 16;
    half8 h0, h1;
#pragma unroll
    for (int k = 0; k < 8; k++) { h0[k] = (_Float16)s[k]; h1[k] = (_Float16)s[k + 8]; }
    *(half8*)(eas + (size_t)p * 16) = h0;
    *(half8*)(eas + (size_t)p * 16 + 8) = h1;
  } else if (i < E + N) {
    int v = i - E;
    csr_src[offs[v] + deg[v]] = v;  // self-loop; attrs filled by loop_attr_kernel
  }
}

// self-loop attr = mean of real incoming slots, written into its slot
__global__ void loop_attr_kernel(const int* __restrict__ offs, const int* __restrict__ deg,
                                 _Float16* __restrict__ eas, int N) {
  int i = blockIdx.x * 256 + threadIdx.x;
  if (i >= N * 16) return;
  int v = i >> 4, k = i & 15;
  int b = offs[v], dg = deg[v];
  float s = 0.f;
  for (int j = 0; j < dg; j++) s += (float)eas[((size_t)(b + j)) * 16 + k];
  eas[((size_t)(b + dg)) * 16 + k] = (_Float16)(s / fmaxf((float)dg, 1.0f));
}

// ---------------- GEMM: C[M,Nfull] = A[M,K](f16) * BT[Nfull,K](f16) + bias ----------------
template <bool RELU, bool OUT_F32>
__global__ __launch_bounds__(256) void gemm_f16(const _Float16* __restrict__ A,
                                                const _Float16* __restrict__ BT,
                                                const float* __restrict__ biasA,
                                                const float* __restrict__ biasB,
                                                void* __restrict__ C,
                                                int M, int K, int Nfull, int ldc) {
  __shared__ _Float16 As[128 * 32];
  __shared__ _Float16 Bs[128 * 32];
  int t = threadIdx.x;
  int m0 = blockIdx.x * 128;
  int n0 = blockIdx.y * 128;
  int l = t & 63, w = t >> 6;
  int wm = w & 1, wn = w >> 1;
  int lr = l & 15, lq = l >> 4;

  f32x4 acc[4][4];
#pragma unroll
  for (int i = 0; i < 4; i++)
#pragma unroll
    for (int j = 0; j < 4; j++) acc[i][j] = (f32x4){0.f, 0.f, 0.f, 0.f};

  int r0 = w * 32 + (l >> 2);
  int cb = (l & 3) * 8;
  const _Float16* Ap = A + (size_t)(m0 + r0) * K + cb;
  const _Float16* Bp = BT + (size_t)(n0 + r0) * K + cb;
  _Float16* AsW = As + w * 32 * 32;
  _Float16* BsW = Bs + w * 32 * 32;

  for (int kk = 0; kk < K; kk += 32) {
    GLOAD_LDS16(Ap, AsW);
    GLOAD_LDS16(Ap + (size_t)16 * K, AsW + 16 * 32);
    GLOAD_LDS16(Bp, BsW);
    GLOAD_LDS16(Bp + (size_t)16 * K, BsW + 16 * 32);
    Ap += 32; Bp += 32;
    __syncthreads();
    half8 af[4], bf[4];
#pragma unroll
    for (int mi = 0; mi < 4; mi++) af[mi] = *(const half8*)&As[(wm * 64 + mi * 16 + lr) * 32 + lq * 8];
#pragma unroll
    for (int ni = 0; ni < 4; ni++) bf[ni] = *(const half8*)&Bs[(wn * 64 + ni * 16 + lr) * 32 + lq * 8];
#pragma unroll
    for (int mi = 0; mi < 4; mi++)
#pragma unroll
      for (int ni = 0; ni < 4; ni++)
        acc[mi][ni] = __builtin_amdgcn_mfma_f32_16x16x32_f16(af[mi], bf[ni], acc[mi][ni], 0, 0, 0);
    __syncthreads();
  }

#pragma unroll
  for (int ni = 0; ni < 4; ni++) {
    int col = n0 + wn * 64 + ni * 16 + lr;
    if (col >= Nfull) continue;
    float bv = (col < 512) ? biasA[col] : biasB[col - 512];
#pragma unroll
    for (int mi = 0; mi < 4; mi++) {
#pragma unroll
      for (int r = 0; r < 4; r++) {
        int row = m0 + wm * 64 + mi * 16 + lq * 4 + r;
        if (row >= M) continue;
        float v = acc[mi][ni][r] + bv;
        if (RELU) v = fmaxf(v, 0.f);
        if (OUT_F32) ((float*)C)[(size_t)row * ldc + col] = v;
        else ((_Float16*)C)[(size_t)row * ldc + col] = (_Float16)v;
      }
    }
  }
}

// ---------------- fused GATv2 edge pass (v2: LDS-We, quad-edge batching) ----------------
// Round-10 finding: the per-lane We fragment (64 VGPRs) was NEVER register-resident —
// the allocator re-read 16KB/edge from L1, which was the real bottleneck. v2 stages We
// in LDS k-major ([16][512] f16, ds_read_b128 lane-stride 16B = conflict-free) and
// batches 4 edges per k-row read (4KB LDS traffic per edge). ef accumulates in packed
// f16 (v_pk_fma); logit dot via fdot2 (f32 acc).

__device__ __forceinline__ void upd(float p, half8 xs, float& m, float& den, float acc[8]) {
  float mn = fmaxf(m, p);
  float sc = __expf(m - mn);
  float al = __expf(p - mn);
  den = den * sc + al;
#pragma unroll
  for (int jj = 0; jj < 8; jj++) acc[jj] = acc[jj] * sc + al * (float)xs[jj];
  m = mn;
}

__global__ __launch_bounds__(256) void gat_fused_kernel(
    const _Float16* __restrict__ xlr,     // [Npad][1024]: 0..511 xl, 512..1023 xr
    const int* __restrict__ csr_src, const int* __restrict__ offs,
    const _Float16* __restrict__ eas,     // [EP+12][16] slot-ordered
    const _Float16* __restrict__ WeK,     // [16][512] f16 (We verbatim)
    const _Float16* __restrict__ att16,   // [4][128] f16
    const float* __restrict__ bias,
    _Float16* __restrict__ hout, int N) {
  __shared__ _Float16 WeL[16 * 512];      // k-major, 16KB
  int t = threadIdx.x;
  int l = t & 63;
  int w = t >> 6;
  int h = l >> 4;
  int c0 = l * 8;

  // stage We -> LDS via async DMA (4 passes x 4 waves x 1KB)
  {
    const _Float16* gW = WeK + w * 512 + l * 8;
    _Float16* lW = WeL + w * 512;          // wave-uniform base; lane*16B auto-added
#pragma unroll
    for (int p = 0; p < 4; p++) GLOAD_LDS16(gW + p * 2048, lW + p * 2048);
  }
  __syncthreads();

  half8 attv = *(const half8*)(att16 + h * 128 + (l & 15) * 8);
  const half2v lk = {(_Float16)0.2f, (_Float16)0.2f};

  int wid = blockIdx.x * 4 + w;
  int nw = gridDim.x * 4;

  for (int v0 = wid; v0 < N; v0 += nw) {
    int v = __builtin_amdgcn_readfirstlane(v0);   // uniform -> s_load for offs/csr/eas
    int b = offs[v], e2 = offs[v + 1];
    half8 xrv = *(const half8*)(xlr + (size_t)v * 1024 + 512 + c0);

    int s0 = csr_src[b], s1 = csr_src[b + 1], s2 = csr_src[b + 2], s3 = csr_src[b + 3];
    half8 xs0 = *(const half8*)(xlr + (size_t)s0 * 1024 + c0);
    half8 xs1 = *(const half8*)(xlr + (size_t)s1 * 1024 + c0);
    half8 xs2 = *(const half8*)(xlr + (size_t)s2 * 1024 + c0);
    half8 xs3 = *(const half8*)(xlr + (size_t)s3 * 1024 + c0);

    float m = -1e30f, den = 0.f;
    float acc[8];
#pragma unroll
    for (int j = 0; j < 8; j++) acc[j] = 0.f;

    for (int j = b; j < e2; j += 4) {
      half8 x0 = xs0, x1 = xs1, x2 = xs2, x3 = xs3;   // snapshot (loaded >=1 iter ago)
      // prefetch next quad's gathers
      int n0 = csr_src[j + 4], n1 = csr_src[j + 5], n2 = csr_src[j + 6], n3 = csr_src[j + 7];
      xs0 = *(const half8*)(xlr + (size_t)n0 * 1024 + c0);
      xs1 = *(const half8*)(xlr + (size_t)n1 * 1024 + c0);
      xs2 = *(const half8*)(xlr + (size_t)n2 * 1024 + c0);
      xs3 = *(const half8*)(xlr + (size_t)n3 * 1024 + c0);
      // current quad's edge attrs (uniform -> scalar loads)
      const half8 a00 = *(const half8*)(eas + (size_t)(j + 0) * 16);
      const half8 a01 = *(const half8*)(eas + (size_t)(j + 0) * 16 + 8);
      const half8 a10 = *(const half8*)(eas + (size_t)(j + 1) * 16);
      const half8 a11 = *(const half8*)(eas + (size_t)(j + 1) * 16 + 8);
      const half8 a20 = *(const half8*)(eas + (size_t)(j + 2) * 16);
      const half8 a21 = *(const half8*)(eas + (size_t)(j + 2) * 16 + 8);
      const half8 a30 = *(const half8*)(eas + (size_t)(j + 3) * 16);
      const half8 a31 = *(const half8*)(eas + (size_t)(j + 3) * 16 + 8);

      half2v e0[4], e1[4], e2v[4], e3[4];
#pragma unroll
      for (int p = 0; p < 4; p++) {
        e0[p] = (half2v){0, 0}; e1[p] = (half2v){0, 0};
        e2v[p] = (half2v){0, 0}; e3[p] = (half2v){0, 0};
      }
      // ef accumulation: one k-row LDS read serves all 4 edges
#pragma unroll
      for (int k = 0; k < 16; k++) {
        half8 wr = *(const half8*)(WeL + k * 512 + c0);   // ds_read_b128, conflict-free
        _Float16 q0 = (k < 8) ? a00[k] : a01[k - 8];
        _Float16 q1 = (k < 8) ? a10[k] : a11[k - 8];
        _Float16 q2 = (k < 8) ? a20[k] : a21[k - 8];
        _Float16 q3 = (k < 8) ? a30[k] : a31[k - 8];
        half2v k0 = {q0, q0}, k1 = {q1, q1}, k2 = {q2, q2}, k3 = {q3, q3};
#pragma unroll
        for (int p = 0; p < 4; p++) {
          half2v wp = H2(wr, p);
          e0[p] += k0 * wp;
          e1[p] += k1 * wp;
          e2v[p] += k2 * wp;
          e3[p] += k3 * wp;
        }
      }
      // logits: val = xs + xr + ef, leaky-relu, dot with att (f32 accumulate)
      float p0 = 0.f, p1 = 0.f, p2 = 0.f, p3 = 0.f;
#pragma unroll
      for (int p = 0; p < 4; p++) {
        half2v xrp = H2(xrv, p);
        half2v ap = H2(attv, p);
        half2v v0 = H2(x0, p) + xrp + e0[p];
        half2v v1 = H2(x1, p) + xrp + e1[p];
        half2v v2 = H2(x2, p) + xrp + e2v[p];
        half2v v3 = H2(x3, p) + xrp + e3[p];
        v0 = __builtin_elementwise_max(v0, v0 * lk);
        v1 = __builtin_elementwise_max(v1, v1 * lk);
        v2 = __builtin_elementwise_max(v2, v2 * lk);
        v3 = __builtin_elementwise_max(v3, v3 * lk);
        p0 = FDOT2(v0, ap, p0);
        p1 = FDOT2(v1, ap, p1);
        p2 = FDOT2(v2, ap, p2);
        p3 = FDOT2(v3, ap, p3);
      }
      p0 = rowsum16(p0); p1 = rowsum16(p1); p2 = rowsum16(p2); p3 = rowsum16(p3);

      upd(p0, x0, m, den, acc);
      if (j + 1 < e2) upd(p1, x1, m, den, acc);
      if (j + 2 < e2) upd(p2, x2, m, den, acc);
      if (j + 3 < e2) upd(p3, x3, m, den, acc);
    }
    float rd = 1.f / (den + 1e-16f);
    half8 o;
#pragma unroll
    for (int jj = 0; jj < 8; jj++) o[jj] = (_Float16)(fmaf(acc[jj], rd, bias[c0 + jj]));
    *(half8*)(hout + (size_t)v * 512 + c0) = o;
  }
}

// ---------------- launcher ----------------

extern "C" void kernel_launch(void* const* d_in, const int* in_sizes, int n_in,
                              void* d_out, int out_size, void* d_ws, size_t ws_size,
                              hipStream_t stream) {
  (void)n_in; (void)out_size; (void)ws_size;
  const float* x    = (const float*)d_in[0];
  const int*   ei   = (const int*)d_in[1];
  const float* ea   = (const float*)d_in[2];
  const float* Wl1  = (const float*)d_in[3];
  const float* bl1  = (const float*)d_in[4];
  const float* Wr1  = (const float*)d_in[5];
  const float* br1  = (const float*)d_in[6];
  const float* We1  = (const float*)d_in[7];
  const float* att1 = (const float*)d_in[8];
  const float* bias1= (const float*)d_in[9];
  const float* Wl2  = (const float*)d_in[10];
  const float* bl2  = (const float*)d_in[11];
  const float* Wr2  = (const float*)d_in[12];
  const float* br2  = (const float*)d_in[13];
  const float* We2  = (const float*)d_in[14];
  const float* att2 = (const float*)d_in[15];
  const float* bias2= (const float*)d_in[16];
  const float* Wd1  = (const float*)d_in[17];
  const float* bd1  = (const float*)d_in[18];
  const float* Wd2  = (const float*)d_in[19];
  const float* bd2  = (const float*)d_in[20];

  const int N = in_sizes[0] / 128;
  const int E = in_sizes[1] / 2;
  const int EP = E + N;
  const int Npad = (N + 127) & ~127;
  const int* src0 = ei;
  const int* dst0 = ei + E;

  char* ws = (char*)d_ws;
  size_t off = 0;
  auto alloc = [&](size_t bytes) -> void* {
    void* p = ws + off;
    off += (bytes + 255) & ~(size_t)255;
    return p;
  };

  int*   deg    = (int*)alloc((size_t)N * 8);
  int*   cnt    = deg + N;
  int*   offs   = (int*)alloc(((size_t)N + 1) * 4);
  int*   csr_src= (int*)alloc(((size_t)EP + 12) * 4);
  _Float16* eas = (_Float16*)alloc(((size_t)EP + 12) * 16 * 2);
  _Float16* x16   = (_Float16*)alloc((size_t)Npad * 128 * 2);
  _Float16* xlr16 = (_Float16*)alloc((size_t)Npad * 1024 * 2);
  _Float16* h16   = (_Float16*)alloc((size_t)Npad * 512 * 2);
  _Float16* WlrT1 = (_Float16*)alloc(1024 * 128 * 2);
  _Float16* WlrT2 = (_Float16*)alloc(1024 * 512 * 2);
  _Float16* WdT1  = (_Float16*)alloc(512 * 512 * 2);
  _Float16* WdT2  = (_Float16*)alloc(128 * 512 * 2);
  _Float16* WeK1  = (_Float16*)alloc(16 * 512 * 2);
  _Float16* WeK2  = (_Float16*)alloc(16 * 512 * 2);
  _Float16* att16_1 = (_Float16*)alloc(512 * 2);
  _Float16* att16_2 = (_Float16*)alloc(512 * 2);
  _Float16* t16   = xlr16;  // decoder hidden reuses xlr buffer (dead by then)

  hipMemsetAsync(deg, 0, (size_t)N * 8, stream);

  // mega prep
  int nx = N * 128;
  int prep_total = nx + 1024 * 128 + 1024 * 512 + 512 * 512 + 64 * 512
                 + 512 * 16 + 512 * 16 + 512 + 512;
  prep_kernel<<<(prep_total + 255) / 256, 256, 0, stream>>>(
      x, x16, nx, Wl1, Wr1, WlrT1, Wl2, Wr2, WlrT2,
      Wd1, WdT1, Wd2, WdT2, We1, WeK1, We2, WeK2,
      att1, att16_1, att2, att16_2);

  // CSR build (csr_fill also writes slot-ordered edge attrs)
  int g;
  g = (E + 255) / 256;  deg_hist_kernel<<<g, 256, 0, stream>>>(dst0, deg, E);
  scan_kernel<<<1, 1024, 0, stream>>>(deg, offs, N);
  g = (EP + 255) / 256;
  csr_fill_kernel<<<g, 256, 0, stream>>>(src0, dst0, ea, offs, deg, cnt, csr_src, eas, E, N);
  g = (N * 16 + 255) / 256;
  loop_attr_kernel<<<g, 256, 0, stream>>>(offs, deg, eas, N);

  dim3 gb(256);
  dim3 ggm((N + 127) / 128, 8);
  dim3 ggd((N + 127) / 128, 4);
  dim3 ggo((N + 127) / 128, 1);

  const int FGRID = 2048;

  // ---- GAT layer 1 ----
  gemm_f16<false, false><<<ggm, gb, 0, stream>>>(x16, WlrT1, bl1, br1, xlr16, N, 128, 1024, 1024);
  gat_fused_kernel<<<FGRID, 256, 0, stream>>>(xlr16, csr_src, offs, eas, WeK1, att16_1, bias1, h16, N);

  // ---- GAT layer 2 ----
  gemm_f16<false, false><<<ggm, gb, 0, stream>>>(h16, WlrT2, bl2, br2, xlr16, N, 512, 1024, 1024);
  gat_fused_kernel<<<FGRID, 256, 0, stream>>>(xlr16, csr_src, offs, eas, WeK2, att16_2, bias2, h16, N);

  // ---- decoder ----
  gemm_f16<true, false><<<ggd, gb, 0, stream>>>(h16, WdT1, bd1, bd1, t16, N, 512, 512, 512);
  gemm_f16<false, true><<<ggo, gb, 0, stream>>>(t16, WdT2, bd2, bd2, d_out, N, 512, 64, 64);
}

// Round 12
// 524.242 us; speedup vs baseline: 1.0288x; 1.0288x over previous
//
#include <hip/hip_runtime.h>
#include <hip/hip_fp16.h>

typedef _Float16 half8 __attribute__((ext_vector_type(8)));
typedef _Float16 half2v __attribute__((ext_vector_type(2)));
typedef float f32x4 __attribute__((ext_vector_type(4)));

#if __has_builtin(__builtin_amdgcn_fdot2)
#define FDOT2(a, b, c) __builtin_amdgcn_fdot2((a), (b), (c), false)
#else
static __device__ __forceinline__ float FDOT2(half2v a, half2v b, float c) {
  return (float)a[0] * (float)b[0] + (float)a[1] * (float)b[1] + c;
}
#endif
#define H2(v8, p) ((half2v){(v8)[2 * (p)], (v8)[2 * (p) + 1]})

// async global->LDS, 16B per lane; dest = lds base (wave-uniform) + lane*16
#define GLOAD_LDS16(gp, lp)                                                        \
  __builtin_amdgcn_global_load_lds(                                                \
      (const __attribute__((address_space(1))) void*)(gp),                         \
      (__attribute__((address_space(3))) void*)(lp), 16, 0, 0)

// 16-lane all-reduce via DPP rotate-accumulate: 4 VALU ops, no LDS pipe.
template <int CTRL>
__device__ __forceinline__ float dpp_add16(float x) {
  int y = __builtin_amdgcn_update_dpp(0, __float_as_int(x), CTRL, 0xf, 0xf, true);
  return x + __int_as_float(y);
}
__device__ __forceinline__ float rowsum16(float x) {
  x = dpp_add16<0x128>(x);  // row_ror:8
  x = dpp_add16<0x124>(x);  // row_ror:4
  x = dpp_add16<0x122>(x);  // row_ror:2
  x = dpp_add16<0x121>(x);  // row_ror:1
  return x;
}

// ---------------- mega prep kernel: x->f16 + weight transposes + f16 casts + deg hist ----------------
__global__ void prep_kernel(const float* __restrict__ x, _Float16* __restrict__ x16, int nx,
                            const float* __restrict__ Wl1, const float* __restrict__ Wr1,
                            _Float16* __restrict__ WlrT1,
                            const float* __restrict__ Wl2, const float* __restrict__ Wr2,
                            _Float16* __restrict__ WlrT2,
                            const float* __restrict__ Wd1, _Float16* __restrict__ WdT1,
                            const float* __restrict__ Wd2, _Float16* __restrict__ WdT2,
                            const float* __restrict__ We1, _Float16* __restrict__ WeK1,
                            const float* __restrict__ We2, _Float16* __restrict__ WeK2,
                            const float* __restrict__ att1, _Float16* __restrict__ att16_1,
                            const float* __restrict__ att2, _Float16* __restrict__ att16_2,
                            const int* __restrict__ dst0, int* __restrict__ deg, int E) {
  int i = blockIdx.x * 256 + threadIdx.x;
  if (i < nx) { x16[i] = (_Float16)x[i]; return; }
  i -= nx;
  if (i < 1024 * 128) {
    int n = i >> 7, k = i & 127;
    float v = (n < 512) ? Wl1[(size_t)k * 512 + n] : Wr1[(size_t)k * 512 + (n - 512)];
    WlrT1[i] = (_Float16)v; return;
  }
  i -= 1024 * 128;
  if (i < 1024 * 512) {
    int n = i >> 9, k = i & 511;
    float v = (n < 512) ? Wl2[(size_t)k * 512 + n] : Wr2[(size_t)k * 512 + (n - 512)];
    WlrT2[i] = (_Float16)v; return;
  }
  i -= 1024 * 512;
  if (i < 512 * 512) { int n = i >> 9, k = i & 511; WdT1[i] = (_Float16)Wd1[(size_t)k * 512 + n]; return; }
  i -= 512 * 512;
  if (i < 64 * 512)  { int n = i >> 9, k = i & 511; WdT2[i] = (_Float16)Wd2[(size_t)k * 64 + n]; return; }
  i -= 64 * 512;
  if (i < 512 * 16)  { WeK1[i] = (_Float16)We1[i]; return; }   // straight [16][512] cast
  i -= 512 * 16;
  if (i < 512 * 16)  { WeK2[i] = (_Float16)We2[i]; return; }
  i -= 512 * 16;
  if (i < 512)       { att16_1[i] = (_Float16)att1[i]; return; }
  i -= 512;
  if (i < 512)       { att16_2[i] = (_Float16)att2[i]; return; }
  i -= 512;
  if (i < E)         { atomicAdd(&deg[dst0[i]], 1); return; }
}

// ---------------- CSR build ----------------
__global__ __launch_bounds__(1024) void scan_kernel(const int* __restrict__ deg, int* __restrict__ offs, int N) {
  __shared__ int part[1024];
  int t = threadIdx.x;
  int chunk = (N + 1023) / 1024;
  int b = t * chunk, e = min(b + chunk, N);
  int s = 0;
  for (int i = b; i < e; i++) s += deg[i] + 1;
  part[t] = s;
  __syncthreads();
  for (int off = 1; off < 1024; off <<= 1) {
    int v = (t >= off) ? part[t - off] : 0;
    __syncthreads();
    part[t] += v;
    __syncthreads();
  }
  int run = (t == 0) ? 0 : part[t - 1];
  for (int i = b; i < e; i++) { offs[i] = run; run += deg[i] + 1; }
  if (t == 1023) offs[N] = part[1023];
}

// scatter src + slot-ordered edge attr (f16) in one pass; self-loop slot marked, +16 pad
__global__ void csr_fill_kernel(const int* __restrict__ src0, const int* __restrict__ dst0,
                                const float* __restrict__ ea,
                                const int* __restrict__ offs, const int* __restrict__ deg,
                                int* __restrict__ cnt, int* __restrict__ csr_src,
                                _Float16* __restrict__ eas, int E, int N) {
  int i = blockIdx.x * 256 + threadIdx.x;
  if (i < 16) {
    csr_src[E + N + i] = 0;
#pragma unroll
    for (int k = 0; k < 16; k++) eas[(size_t)(E + N + i) * 16 + k] = (_Float16)0.f;
  }
  if (i < E) {
    int d = dst0[i];
    int p = offs[d] + atomicAdd(&cnt[d], 1);
    csr_src[p] = src0[i];
    const float* s = ea + (size_t)i * 16;
    half8 h0, h1;
#pragma unroll
    for (int k = 0; k < 8; k++) { h0[k] = (_Float16)s[k]; h1[k] = (_Float16)s[k + 8]; }
    *(half8*)(eas + (size_t)p * 16) = h0;
    *(half8*)(eas + (size_t)p * 16 + 8) = h1;
  } else if (i < E + N) {
    int v = i - E;
    csr_src[offs[v] + deg[v]] = v;  // self-loop; attrs filled by loop_attr_kernel
  }
}

// self-loop attr = mean of real incoming slots, written into its slot
__global__ void loop_attr_kernel(const int* __restrict__ offs, const int* __restrict__ deg,
                                 _Float16* __restrict__ eas, int N) {
  int i = blockIdx.x * 256 + threadIdx.x;
  if (i >= N * 16) return;
  int v = i >> 4, k = i & 15;
  int b = offs[v], dg = deg[v];
  float s = 0.f;
  for (int j = 0; j < dg; j++) s += (float)eas[((size_t)(b + j)) * 16 + k];
  eas[((size_t)(b + dg)) * 16 + k] = (_Float16)(s / fmaxf((float)dg, 1.0f));
}

// ---------------- GEMM: C[M,Nfull] = A[M,K](f16) * BT[Nfull,K](f16) + bias ----------------
template <bool RELU, bool OUT_F32>
__global__ __launch_bounds__(256) void gemm_f16(const _Float16* __restrict__ A,
                                                const _Float16* __restrict__ BT,
                                                const float* __restrict__ biasA,
                                                const float* __restrict__ biasB,
                                                void* __restrict__ C,
                                                int M, int K, int Nfull, int ldc) {
  __shared__ _Float16 As[128 * 32];
  __shared__ _Float16 Bs[128 * 32];
  int t = threadIdx.x;
  int m0 = blockIdx.x * 128;
  int n0 = blockIdx.y * 128;
  int l = t & 63, w = t >> 6;
  int wm = w & 1, wn = w >> 1;
  int lr = l & 15, lq = l >> 4;

  f32x4 acc[4][4];
#pragma unroll
  for (int i = 0; i < 4; i++)
#pragma unroll
    for (int j = 0; j < 4; j++) acc[i][j] = (f32x4){0.f, 0.f, 0.f, 0.f};

  int r0 = w * 32 + (l >> 2);
  int cb = (l & 3) * 8;
  const _Float16* Ap = A + (size_t)(m0 + r0) * K + cb;
  const _Float16* Bp = BT + (size_t)(n0 + r0) * K + cb;
  _Float16* AsW = As + w * 32 * 32;
  _Float16* BsW = Bs + w * 32 * 32;

  for (int kk = 0; kk < K; kk += 32) {
    GLOAD_LDS16(Ap, AsW);
    GLOAD_LDS16(Ap + (size_t)16 * K, AsW + 16 * 32);
    GLOAD_LDS16(Bp, BsW);
    GLOAD_LDS16(Bp + (size_t)16 * K, BsW + 16 * 32);
    Ap += 32; Bp += 32;
    __syncthreads();
    half8 af[4], bf[4];
#pragma unroll
    for (int mi = 0; mi < 4; mi++) af[mi] = *(const half8*)&As[(wm * 64 + mi * 16 + lr) * 32 + lq * 8];
#pragma unroll
    for (int ni = 0; ni < 4; ni++) bf[ni] = *(const half8*)&Bs[(wn * 64 + ni * 16 + lr) * 32 + lq * 8];
#pragma unroll
    for (int mi = 0; mi < 4; mi++)
#pragma unroll
      for (int ni = 0; ni < 4; ni++)
        acc[mi][ni] = __builtin_amdgcn_mfma_f32_16x16x32_f16(af[mi], bf[ni], acc[mi][ni], 0, 0, 0);
    __syncthreads();
  }

#pragma unroll
  for (int ni = 0; ni < 4; ni++) {
    int col = n0 + wn * 64 + ni * 16 + lr;
    if (col >= Nfull) continue;
    float bv = (col < 512) ? biasA[col] : biasB[col - 512];
#pragma unroll
    for (int mi = 0; mi < 4; mi++) {
#pragma unroll
      for (int r = 0; r < 4; r++) {
        int row = m0 + wm * 64 + mi * 16 + lq * 4 + r;
        if (row >= M) continue;
        float v = acc[mi][ni][r] + bv;
        if (RELU) v = fmaxf(v, 0.f);
        if (OUT_F32) ((float*)C)[(size_t)row * ldc + col] = v;
        else ((_Float16*)C)[(size_t)row * ldc + col] = (_Float16)v;
      }
    }
  }
}

// ---------------- fused GATv2 edge pass (v3: LDS-We, quad batch, 2-deep scalar pipeline) ----------------
// Round-11 finding: VALUBusy pinned at ~67% because the per-quad scalar loads
// (eas attrs s_load_dwordx16, csr_src indices) were consumed in the same
// iteration they were issued (~400cyc SMEM stall per quad). v3 pipelines:
// indices 2 quads ahead, attrs + xs gathers 1 quad ahead.

__device__ __forceinline__ void upd(float p, half8 xs, float& m, float& den, float acc[8]) {
  float mn = fmaxf(m, p);
  float sc = __expf(m - mn);
  float al = __expf(p - mn);
  den = den * sc + al;
#pragma unroll
  for (int jj = 0; jj < 8; jj++) acc[jj] = acc[jj] * sc + al * (float)xs[jj];
  m = mn;
}

__global__ __launch_bounds__(256) void gat_fused_kernel(
    const _Float16* __restrict__ xlr,     // [Npad][1024]: 0..511 xl, 512..1023 xr
    const int* __restrict__ csr_src, const int* __restrict__ offs,
    const _Float16* __restrict__ eas,     // [EP+16][16] slot-ordered
    const _Float16* __restrict__ WeK,     // [16][512] f16 (We verbatim)
    const _Float16* __restrict__ att16,   // [4][128] f16
    const float* __restrict__ bias,
    _Float16* __restrict__ hout, int N) {
  __shared__ _Float16 WeL[16 * 512];      // k-major, 16KB
  int t = threadIdx.x;
  int l = t & 63;
  int w = t >> 6;
  int h = l >> 4;
  int c0 = l * 8;

  {
    const _Float16* gW = WeK + w * 512 + l * 8;
    _Float16* lW = WeL + w * 512;
#pragma unroll
    for (int p = 0; p < 4; p++) GLOAD_LDS16(gW + p * 2048, lW + p * 2048);
  }
  __syncthreads();

  half8 attv = *(const half8*)(att16 + h * 128 + (l & 15) * 8);
  const half2v lk = {(_Float16)0.2f, (_Float16)0.2f};

  int wid = blockIdx.x * 4 + w;
  int nw = gridDim.x * 4;

  for (int v0 = wid; v0 < N; v0 += nw) {
    int v = __builtin_amdgcn_readfirstlane(v0);
    int b = offs[v], e2 = offs[v + 1];
    half8 xrv = *(const half8*)(xlr + (size_t)v * 1024 + 512 + c0);

    // quad 0 indices + data (prologue stall, once per node)
    int s0 = csr_src[b], s1 = csr_src[b + 1], s2 = csr_src[b + 2], s3 = csr_src[b + 3];
    half8 xs0 = *(const half8*)(xlr + (size_t)s0 * 1024 + c0);
    half8 xs1 = *(const half8*)(xlr + (size_t)s1 * 1024 + c0);
    half8 xs2 = *(const half8*)(xlr + (size_t)s2 * 1024 + c0);
    half8 xs3 = *(const half8*)(xlr + (size_t)s3 * 1024 + c0);
    half8 a00 = *(const half8*)(eas + (size_t)b * 16);
    half8 a01 = *(const half8*)(eas + (size_t)b * 16 + 8);
    half8 a10 = *(const half8*)(eas + (size_t)(b + 1) * 16);
    half8 a11 = *(const half8*)(eas + (size_t)(b + 1) * 16 + 8);
    half8 a20 = *(const half8*)(eas + (size_t)(b + 2) * 16);
    half8 a21 = *(const half8*)(eas + (size_t)(b + 2) * 16 + 8);
    half8 a30 = *(const half8*)(eas + (size_t)(b + 3) * 16);
    half8 a31 = *(const half8*)(eas + (size_t)(b + 3) * 16 + 8);
    // quad 1 indices
    int t0 = csr_src[b + 4], t1 = csr_src[b + 5], t2 = csr_src[b + 6], t3 = csr_src[b + 7];

    float m = -1e30f, den = 0.f;
    float acc[8];
#pragma unroll
    for (int j = 0; j < 8; j++) acc[j] = 0.f;

    for (int j = b; j < e2; j += 4) {
      // issue next quad's xs gathers (indices loaded last iteration)
      half8 nx0 = *(const half8*)(xlr + (size_t)t0 * 1024 + c0);
      half8 nx1 = *(const half8*)(xlr + (size_t)t1 * 1024 + c0);
      half8 nx2 = *(const half8*)(xlr + (size_t)t2 * 1024 + c0);
      half8 nx3 = *(const half8*)(xlr + (size_t)t3 * 1024 + c0);
      // issue next quad's attr s_loads (uniform, 128B contiguous)
      half8 n00 = *(const half8*)(eas + (size_t)(j + 4) * 16);
      half8 n01 = *(const half8*)(eas + (size_t)(j + 4) * 16 + 8);
      half8 n10 = *(const half8*)(eas + (size_t)(j + 5) * 16);
      half8 n11 = *(const half8*)(eas + (size_t)(j + 5) * 16 + 8);
      half8 n20 = *(const half8*)(eas + (size_t)(j + 6) * 16);
      half8 n21 = *(const half8*)(eas + (size_t)(j + 6) * 16 + 8);
      half8 n30 = *(const half8*)(eas + (size_t)(j + 7) * 16);
      half8 n31 = *(const half8*)(eas + (size_t)(j + 7) * 16 + 8);
      // indices for quad j+8 (2 ahead)
      int u0 = csr_src[j + 8], u1 = csr_src[j + 9], u2 = csr_src[j + 10], u3 = csr_src[j + 11];

      // ---- compute on current quad (all operands loaded >=1 iteration ago) ----
      half2v e0[4], e1[4], e2v[4], e3[4];
#pragma unroll
      for (int p = 0; p < 4; p++) {
        e0[p] = (half2v){0, 0}; e1[p] = (half2v){0, 0};
        e2v[p] = (half2v){0, 0}; e3[p] = (half2v){0, 0};
      }
#pragma unroll
      for (int k = 0; k < 16; k++) {
        half8 wr = *(const half8*)(WeL + k * 512 + c0);   // ds_read_b128, conflict-free
        _Float16 q0 = (k < 8) ? a00[k] : a01[k - 8];
        _Float16 q1 = (k < 8) ? a10[k] : a11[k - 8];
        _Float16 q2 = (k < 8) ? a20[k] : a21[k - 8];
        _Float16 q3 = (k < 8) ? a30[k] : a31[k - 8];
        half2v k0 = {q0, q0}, k1 = {q1, q1}, k2 = {q2, q2}, k3 = {q3, q3};
#pragma unroll
        for (int p = 0; p < 4; p++) {
          half2v wp = H2(wr, p);
          e0[p] += k0 * wp;
          e1[p] += k1 * wp;
          e2v[p] += k2 * wp;
          e3[p] += k3 * wp;
        }
      }
      float p0 = 0.f, p1 = 0.f, p2 = 0.f, p3 = 0.f;
#pragma unroll
      for (int p = 0; p < 4; p++) {
        half2v xrp = H2(xrv, p);
        half2v ap = H2(attv, p);
        half2v v0 = H2(xs0, p) + xrp + e0[p];
        half2v v1 = H2(xs1, p) + xrp + e1[p];
        half2v v2 = H2(xs2, p) + xrp + e2v[p];
        half2v v3 = H2(xs3, p) + xrp + e3[p];
        v0 = __builtin_elementwise_max(v0, v0 * lk);
        v1 = __builtin_elementwise_max(v1, v1 * lk);
        v2 = __builtin_elementwise_max(v2, v2 * lk);
        v3 = __builtin_elementwise_max(v3, v3 * lk);
        p0 = FDOT2(v0, ap, p0);
        p1 = FDOT2(v1, ap, p1);
        p2 = FDOT2(v2, ap, p2);
        p3 = FDOT2(v3, ap, p3);
      }
      p0 = rowsum16(p0); p1 = rowsum16(p1); p2 = rowsum16(p2); p3 = rowsum16(p3);

      upd(p0, xs0, m, den, acc);
      if (j + 1 < e2) upd(p1, xs1, m, den, acc);
      if (j + 2 < e2) upd(p2, xs2, m, den, acc);
      if (j + 3 < e2) upd(p3, xs3, m, den, acc);

      // ---- rotate pipeline ----
      xs0 = nx0; xs1 = nx1; xs2 = nx2; xs3 = nx3;
      a00 = n00; a01 = n01; a10 = n10; a11 = n11;
      a20 = n20; a21 = n21; a30 = n30; a31 = n31;
      t0 = u0; t1 = u1; t2 = u2; t3 = u3;
    }
    float rd = 1.f / (den + 1e-16f);
    half8 o;
#pragma unroll
    for (int jj = 0; jj < 8; jj++) o[jj] = (_Float16)(fmaf(acc[jj], rd, bias[c0 + jj]));
    *(half8*)(hout + (size_t)v * 512 + c0) = o;
  }
}

// ---------------- launcher ----------------

extern "C" void kernel_launch(void* const* d_in, const int* in_sizes, int n_in,
                              void* d_out, int out_size, void* d_ws, size_t ws_size,
                              hipStream_t stream) {
  (void)n_in; (void)out_size; (void)ws_size;
  const float* x    = (const float*)d_in[0];
  const int*   ei   = (const int*)d_in[1];
  const float* ea   = (const float*)d_in[2];
  const float* Wl1  = (const float*)d_in[3];
  const float* bl1  = (const float*)d_in[4];
  const float* Wr1  = (const float*)d_in[5];
  const float* br1  = (const float*)d_in[6];
  const float* We1  = (const float*)d_in[7];
  const float* att1 = (const float*)d_in[8];
  const float* bias1= (const float*)d_in[9];
  const float* Wl2  = (const float*)d_in[10];
  const float* bl2  = (const float*)d_in[11];
  const float* Wr2  = (const float*)d_in[12];
  const float* br2  = (const float*)d_in[13];
  const float* We2  = (const float*)d_in[14];
  const float* att2 = (const float*)d_in[15];
  const float* bias2= (const float*)d_in[16];
  const float* Wd1  = (const float*)d_in[17];
  const float* bd1  = (const float*)d_in[18];
  const float* Wd2  = (const float*)d_in[19];
  const float* bd2  = (const float*)d_in[20];

  const int N = in_sizes[0] / 128;
  const int E = in_sizes[1] / 2;
  const int EP = E + N;
  const int Npad = (N + 127) & ~127;
  const int* src0 = ei;
  const int* dst0 = ei + E;

  char* ws = (char*)d_ws;
  size_t off = 0;
  auto alloc = [&](size_t bytes) -> void* {
    void* p = ws + off;
    off += (bytes + 255) & ~(size_t)255;
    return p;
  };

  int*   deg    = (int*)alloc((size_t)N * 8);
  int*   cnt    = deg + N;
  int*   offs   = (int*)alloc(((size_t)N + 1) * 4);
  int*   csr_src= (int*)alloc(((size_t)EP + 16) * 4);
  _Float16* eas = (_Float16*)alloc(((size_t)EP + 16) * 16 * 2);
  _Float16* x16   = (_Float16*)alloc((size_t)Npad * 128 * 2);
  _Float16* xlr16 = (_Float16*)alloc((size_t)Npad * 1024 * 2);
  _Float16* h16   = (_Float16*)alloc((size_t)Npad * 512 * 2);
  _Float16* WlrT1 = (_Float16*)alloc(1024 * 128 * 2);
  _Float16* WlrT2 = (_Float16*)alloc(1024 * 512 * 2);
  _Float16* WdT1  = (_Float16*)alloc(512 * 512 * 2);
  _Float16* WdT2  = (_Float16*)alloc(128 * 512 * 2);
  _Float16* WeK1  = (_Float16*)alloc(16 * 512 * 2);
  _Float16* WeK2  = (_Float16*)alloc(16 * 512 * 2);
  _Float16* att16_1 = (_Float16*)alloc(512 * 2);
  _Float16* att16_2 = (_Float16*)alloc(512 * 2);
  _Float16* t16   = xlr16;  // decoder hidden reuses xlr buffer (dead by then)

  hipMemsetAsync(deg, 0, (size_t)N * 8, stream);

  // mega prep (now also does the degree histogram — saves a launch)
  int nx = N * 128;
  int prep_base = nx + 1024 * 128 + 1024 * 512 + 512 * 512 + 64 * 512
                + 512 * 16 + 512 * 16 + 512 + 512;
  int prep_total = prep_base + E;
  prep_kernel<<<(prep_total + 255) / 256, 256, 0, stream>>>(
      x, x16, nx, Wl1, Wr1, WlrT1, Wl2, Wr2, WlrT2,
      Wd1, WdT1, Wd2, WdT2, We1, WeK1, We2, WeK2,
      att1, att16_1, att2, att16_2, dst0, deg, E);

  // CSR build (csr_fill also writes slot-ordered edge attrs)
  int g;
  scan_kernel<<<1, 1024, 0, stream>>>(deg, offs, N);
  g = (EP + 255) / 256;
  csr_fill_kernel<<<g, 256, 0, stream>>>(src0, dst0, ea, offs, deg, cnt, csr_src, eas, E, N);
  g = (N * 16 + 255) / 256;
  loop_attr_kernel<<<g, 256, 0, stream>>>(offs, deg, eas, N);

  dim3 gb(256);
  dim3 ggm((N + 127) / 128, 8);
  dim3 ggd((N + 127) / 128, 4);
  dim3 ggo((N + 127) / 128, 1);

  const int FGRID = 2048;

  // ---- GAT layer 1 ----
  gemm_f16<false, false><<<ggm, gb, 0, stream>>>(x16, WlrT1, bl1, br1, xlr16, N, 128, 1024, 1024);
  gat_fused_kernel<<<FGRID, 256, 0, stream>>>(xlr16, csr_src, offs, eas, WeK1, att16_1, bias1, h16, N);

  // ---- GAT layer 2 ----
  gemm_f16<false, false><<<ggm, gb, 0, stream>>>(h16, WlrT2, bl2, br2, xlr16, N, 512, 1024, 1024);
  gat_fused_kernel<<<FGRID, 256, 0, stream>>>(xlr16, csr_src, offs, eas, WeK2, att16_2, bias2, h16, N);

  // ---- decoder ----
  gemm_f16<true, false><<<ggd, gb, 0, stream>>>(h16, WdT1, bd1, bd1, t16, N, 512, 512, 512);
  gemm_f16<false, true><<<ggo, gb, 0, stream>>>(t16, WdT2, bd2, bd2, d_out, N, 512, 64, 64);
}